// Round 2
// baseline (877.780 us; speedup 1.0000x reference)
//
#include <hip/hip_runtime.h>
#include <math.h>

#define DQ 2048
#define CDIM 512
#define NKEYS 256
#define KSEL 32

// ---------------- q = X * Wq^T  (fp32 vector GEMM) ----------------
// A = X (2048x512), B = Wq (2048x512), both row-major K-contig -> C (2048x2048)
__global__ __launch_bounds__(256) void qgemm_f32(
    const float* __restrict__ X, const float* __restrict__ W, float* __restrict__ Q) {
  __shared__ float As[32 * 68];  // [k][m], pad 68
  __shared__ float Bs[32 * 68];  // [k][n]
  const int tid = threadIdx.x;
  const int m0 = blockIdx.x * 64, n0 = blockIdx.y * 64;
  const int tx = tid & 15, ty = tid >> 4;
  const int srow = tid & 63, kg = tid >> 6;  // staging: row + k-group
  float acc[4][4] = {};
  for (int kt = 0; kt < CDIM; kt += 32) {
    float4 a0 = *(const float4*)&X[(size_t)(m0 + srow) * CDIM + kt + kg * 8];
    float4 a1 = *(const float4*)&X[(size_t)(m0 + srow) * CDIM + kt + kg * 8 + 4];
    float4 b0 = *(const float4*)&W[(size_t)(n0 + srow) * CDIM + kt + kg * 8];
    float4 b1 = *(const float4*)&W[(size_t)(n0 + srow) * CDIM + kt + kg * 8 + 4];
    __syncthreads();  // previous iteration's reads complete before overwrite
    As[(kg * 8 + 0) * 68 + srow] = a0.x; As[(kg * 8 + 1) * 68 + srow] = a0.y;
    As[(kg * 8 + 2) * 68 + srow] = a0.z; As[(kg * 8 + 3) * 68 + srow] = a0.w;
    As[(kg * 8 + 4) * 68 + srow] = a1.x; As[(kg * 8 + 5) * 68 + srow] = a1.y;
    As[(kg * 8 + 6) * 68 + srow] = a1.z; As[(kg * 8 + 7) * 68 + srow] = a1.w;
    Bs[(kg * 8 + 0) * 68 + srow] = b0.x; Bs[(kg * 8 + 1) * 68 + srow] = b0.y;
    Bs[(kg * 8 + 2) * 68 + srow] = b0.z; Bs[(kg * 8 + 3) * 68 + srow] = b0.w;
    Bs[(kg * 8 + 4) * 68 + srow] = b1.x; Bs[(kg * 8 + 5) * 68 + srow] = b1.y;
    Bs[(kg * 8 + 6) * 68 + srow] = b1.z; Bs[(kg * 8 + 7) * 68 + srow] = b1.w;
    __syncthreads();
    #pragma unroll
    for (int kk = 0; kk < 32; ++kk) {
      float4 av = *(const float4*)&As[kk * 68 + ty * 4];
      float4 bv = *(const float4*)&Bs[kk * 68 + tx * 4];
      acc[0][0] += av.x * bv.x; acc[0][1] += av.x * bv.y; acc[0][2] += av.x * bv.z; acc[0][3] += av.x * bv.w;
      acc[1][0] += av.y * bv.x; acc[1][1] += av.y * bv.y; acc[1][2] += av.y * bv.z; acc[1][3] += av.y * bv.w;
      acc[2][0] += av.z * bv.x; acc[2][1] += av.z * bv.y; acc[2][2] += av.z * bv.z; acc[2][3] += av.z * bv.w;
      acc[3][0] += av.w * bv.x; acc[3][1] += av.w * bv.y; acc[3][2] += av.w * bv.z; acc[3][3] += av.w * bv.w;
    }
  }
  for (int i = 0; i < 4; ++i) {
    float4 c4 = make_float4(acc[i][0], acc[i][1], acc[i][2], acc[i][3]);
    *(float4*)&Q[(size_t)(m0 + ty * 4 + i) * DQ + n0 + tx * 4] = c4;
  }
}

// ---------------- LayerNorm over contiguous 128-groups, in place ----------------
__global__ __launch_bounds__(256) void ln_kernel(
    float* __restrict__ Q, const float* __restrict__ gamma, const float* __restrict__ beta) {
  const int g = blockIdx.x * 4 + (threadIdx.x >> 6);  // 32768 groups of 128
  const int lane = threadIdx.x & 63;
  float2 v = *(float2*)(&Q[(size_t)g * 128 + lane * 2]);
  float s = v.x + v.y, sq = v.x * v.x + v.y * v.y;
  #pragma unroll
  for (int m = 1; m < 64; m <<= 1) {
    s += __shfl_xor(s, m, 64);
    sq += __shfl_xor(sq, m, 64);
  }
  float mean = s * (1.0f / 128.0f);
  float var = sq * (1.0f / 128.0f) - mean * mean;
  float rs = 1.0f / sqrtf(var + 1e-5f);
  float g0 = gamma[lane * 2], g1 = gamma[lane * 2 + 1];
  float b0 = beta[lane * 2], b1 = beta[lane * 2 + 1];
  v.x = (v.x - mean) * rs * g0 + b0;
  v.y = (v.y - mean) * rs * g1 + b1;
  *(float2*)(&Q[(size_t)g * 128 + lane * 2]) = v;
}

// ---------------- dots (fp32) + stage-1 top-32-of-256 ----------------
// block: 512 threads (8 waves) per (hp, 64-token chunk). lane = token.
__global__ __launch_bounds__(512) void dots_topk1(
    const float* __restrict__ Q, const float* __restrict__ keys,
    float* __restrict__ s1s, int* __restrict__ s1i) {
  const int hp = blockIdx.x & 15;     // h*2+p
  const int chunk = blockIdx.x >> 4;  // 0..31
  const int h = hp >> 1, p = hp & 1;
  const int t0 = chunk * 64;
  __shared__ float Qs[64 * 132];
  __shared__ float Ss[64 * 257];
  const int tid = threadIdx.x;
  const int wave = tid >> 6, lane = tid & 63;
  // stage q tile (64 tokens x 128 dims)
  {
    const int tok = tid >> 3, c = (tid & 7) * 16;
    const float* src = &Q[(size_t)(t0 + tok) * DQ + p * 1024 + h * 128 + c];
    float* dst = &Qs[tok * 132 + c];
    #pragma unroll
    for (int i = 0; i < 4; ++i)
      *(float4*)(dst + i * 4) = *(const float4*)(src + i * 4);
  }
  __syncthreads();
  // compute: wave handles key groups kb = (g*8+wave)*16, g in {0,1}
  const float* kh = keys + (size_t)h * 65536 + p * 128;  // + n*256 + d
  for (int g = 0; g < 2; ++g) {
    const int kb = __builtin_amdgcn_readfirstlane((g * 8 + wave) * 16);
    float acc[16];
    #pragma unroll
    for (int i = 0; i < 16; ++i) acc[i] = 0.f;
    #pragma unroll 2
    for (int dq = 0; dq < 32; ++dq) {
      float4 qv = *(const float4*)&Qs[lane * 132 + dq * 4];
      #pragma unroll
      for (int kk = 0; kk < 16; ++kk) {
        float4 kv = *(const float4*)(kh + (size_t)(kb + kk) * 256 + dq * 4);
        acc[kk] += qv.x * kv.x + qv.y * kv.y + qv.z * kv.z + qv.w * kv.w;
      }
    }
    #pragma unroll
    for (int kk = 0; kk < 16; ++kk) Ss[lane * 257 + kb + kk] = acc[kk];
  }
  __syncthreads();
  // selection: wave handles tokens wave*8 .. +8, top-32-of-256 each
  for (int tt = 0; tt < 8; ++tt) {
    const int tok = wave * 8 + tt;
    float v[4];
    #pragma unroll
    for (int s = 0; s < 4; ++s) v[s] = Ss[tok * 257 + lane + 64 * s];
    const int inst = (t0 + tok) * 16 + hp;
    for (int r = 0; r < KSEL; ++r) {
      float bv = v[0]; int bi = lane;
      #pragma unroll
      for (int s = 1; s < 4; ++s)
        if (v[s] > bv) { bv = v[s]; bi = lane + 64 * s; }
      #pragma unroll
      for (int m = 1; m < 64; m <<= 1) {
        float ov = __shfl_xor(bv, m, 64);
        int oi = __shfl_xor(bi, m, 64);
        if (ov > bv || (ov == bv && oi < bi)) { bv = ov; bi = oi; }
      }
      if ((bi & 63) == lane) v[bi >> 6] = -INFINITY;
      if (lane == r) { s1s[(size_t)inst * KSEL + r] = bv; s1i[(size_t)inst * KSEL + r] = bi; }
    }
  }
}

// ---------------- stage-2: combine 32x32, top-32-of-1024, softmax ----------------
__global__ __launch_bounds__(256) void stage2_kernel(
    const float* __restrict__ s1s, const int* __restrict__ s1i,
    float* __restrict__ wgt, int* __restrict__ vidx) {
  const int th = blockIdx.x * 4 + (threadIdx.x >> 6);
  const int lane = threadIdx.x & 63;
  const int bx = (th * 2) * KSEL;  // p=0
  const int by = bx + KSEL;        // p=1
  const int i = lane >> 1;
  const int j0 = (lane & 1) * 16;
  float sx = s1s[bx + i];
  float cand[16];
  #pragma unroll
  for (int m = 0; m < 16; ++m) cand[m] = sx + s1s[by + j0 + m];
  unsigned valid = 0xffffu;
  float selv = 0.f; int self_ = 0;
  for (int r = 0; r < KSEL; ++r) {
    float bv = -INFINITY; int bm = 0;
    #pragma unroll
    for (int m = 0; m < 16; ++m) {
      bool ok = ((valid >> m) & 1u) != 0;
      if (ok && cand[m] > bv) { bv = cand[m]; bm = m; }
    }
    int bf = i * 32 + j0 + bm;
    #pragma unroll
    for (int m = 1; m < 64; m <<= 1) {
      float ov = __shfl_xor(bv, m, 64);
      int of = __shfl_xor(bf, m, 64);
      if (ov > bv || (ov == bv && of < bf)) { bv = ov; bf = of; }
    }
    int owner = ((bf >> 5) << 1) | ((bf >> 4) & 1);
    if (lane == owner) valid &= ~(1u << (bf & 15));
    if (lane == r) { selv = bv; self_ = bf; }
  }
  float mx = __shfl(selv, 0, 64);
  float e = (lane < KSEL) ? expf(selv - mx) : 0.f;
  float es = e;
  #pragma unroll
  for (int m = 1; m < 64; m <<= 1) es += __shfl_xor(es, m, 64);
  if (lane < KSEL) {
    int ci = self_ >> 5, cj = self_ & 31;
    int vi = s1i[bx + ci] * NKEYS + s1i[by + cj];
    wgt[(size_t)th * KSEL + lane] = e / es;
    vidx[(size_t)th * KSEL + lane] = vi;
  }
}

// ---------------- gather + weighted sum -> fp32 out ----------------
__global__ __launch_bounds__(256) void gather_kernel(
    const float* __restrict__ wgt, const int* __restrict__ vidx,
    const float* __restrict__ values, float* __restrict__ out) {
  const int t = blockIdx.x;
  const int tid = threadIdx.x;
  __shared__ float ws_[256];
  __shared__ int vs_[256];
  ws_[tid] = wgt[(size_t)t * 256 + tid];
  vs_[tid] = vidx[(size_t)t * 256 + tid];
  __syncthreads();
  float a0 = 0.f, a1 = 0.f;
  #pragma unroll 8
  for (int e = 0; e < 256; ++e) {
    float2 vv = *(const float2*)(values + (size_t)vs_[e] * CDIM + tid * 2);
    float wv = ws_[e];
    a0 += wv * vv.x;
    a1 += wv * vv.y;
  }
  float2 r = make_float2(a0, a1);
  *(float2*)(out + (size_t)t * CDIM + tid * 2) = r;
}

extern "C" void kernel_launch(void* const* d_in, const int* in_sizes, int n_in,
                              void* d_out, int out_size, void* d_ws, size_t ws_size,
                              hipStream_t stream) {
  const float* X      = (const float*)d_in[0];  // (2,1024,512)
  const float* W      = (const float*)d_in[1];  // (2048,512)
  const float* keys   = (const float*)d_in[2];  // (8,256,2,128)
  const float* values = (const float*)d_in[3];  // (65536,512)
  const float* gamma  = (const float*)d_in[4];  // (128,)
  const float* beta   = (const float*)d_in[5];  // (128,)
  char* ws = (char*)d_ws;
  float* Q   = (float*)(ws);                 // 16 MB (dead after dots_topk1)
  float* s1s = (float*)(ws + (16u << 20));   // 4 MB
  int*   s1i = (int*)  (ws + (20u << 20));   // 4 MB
  float* wgt = (float*)(ws);                 // 2 MB (reuses dead Q region)
  int*   vix = (int*)  (ws + (2u << 20));    // 2 MB

  qgemm_f32<<<dim3(32, 32), 256, 0, stream>>>(X, W, Q);
  ln_kernel<<<8192, 256, 0, stream>>>(Q, gamma, beta);
  dots_topk1<<<512, 512, 0, stream>>>(Q, keys, s1s, s1i);
  stage2_kernel<<<4096, 256, 0, stream>>>(s1s, s1i, wgt, vix);
  gather_kernel<<<2048, 256, 0, stream>>>(wgt, vix, values, (float*)d_out);
}

// Round 3
// 835.975 us; speedup vs baseline: 1.0500x; 1.0500x over previous
//
#include <hip/hip_runtime.h>
#include <math.h>

#define DQ 2048
#define CDIM 512
#define NKEYS 256
#define KSEL 32

// ---------------- q = LN(X * Wq^T) fused (fp32 vector GEMM + groupwise LN) ----------------
// Tile 64(M) x 128(N), K=512. N-tile == one LN group (128 cols) per row.
__global__ __launch_bounds__(256) void qgemm_ln(
    const float* __restrict__ X, const float* __restrict__ W,
    const float* __restrict__ gamma, const float* __restrict__ beta,
    float* __restrict__ Q) {
  __shared__ float As[16 * 68];   // [k][m] transposed, pad 68
  __shared__ float Bs[16 * 132];  // [k][n] transposed, pad 132
  const int tid = threadIdx.x;
  const int m0 = blockIdx.x * 64, n0 = blockIdx.y * 128;
  const int tx = tid & 15, ty = tid >> 4;       // compute: rows ty*4.., cols tx*8..
  const int am = tid >> 2, ak = (tid & 3) * 4;  // A staging: 64m x 16k
  const int bn = tid >> 1, bk = (tid & 1) * 8;  // B staging: 128n x 16k
  float acc[4][8] = {};
  for (int kt = 0; kt < CDIM; kt += 16) {
    float4 av  = *(const float4*)&X[(size_t)(m0 + am) * CDIM + kt + ak];
    float4 bv0 = *(const float4*)&W[(size_t)(n0 + bn) * CDIM + kt + bk];
    float4 bv1 = *(const float4*)&W[(size_t)(n0 + bn) * CDIM + kt + bk + 4];
    __syncthreads();
    As[(ak + 0) * 68 + am] = av.x; As[(ak + 1) * 68 + am] = av.y;
    As[(ak + 2) * 68 + am] = av.z; As[(ak + 3) * 68 + am] = av.w;
    Bs[(bk + 0) * 132 + bn] = bv0.x; Bs[(bk + 1) * 132 + bn] = bv0.y;
    Bs[(bk + 2) * 132 + bn] = bv0.z; Bs[(bk + 3) * 132 + bn] = bv0.w;
    Bs[(bk + 4) * 132 + bn] = bv1.x; Bs[(bk + 5) * 132 + bn] = bv1.y;
    Bs[(bk + 6) * 132 + bn] = bv1.z; Bs[(bk + 7) * 132 + bn] = bv1.w;
    __syncthreads();
    #pragma unroll
    for (int kk = 0; kk < 16; ++kk) {
      float4 a4  = *(const float4*)&As[kk * 68 + ty * 4];
      float4 b4a = *(const float4*)&Bs[kk * 132 + tx * 8];
      float4 b4b = *(const float4*)&Bs[kk * 132 + tx * 8 + 4];
      const float ar[4] = {a4.x, a4.y, a4.z, a4.w};
      const float br[8] = {b4a.x, b4a.y, b4a.z, b4a.w, b4b.x, b4b.y, b4b.z, b4b.w};
      #pragma unroll
      for (int i = 0; i < 4; ++i)
        #pragma unroll
        for (int j = 0; j < 8; ++j)
          acc[i][j] += ar[i] * br[j];
    }
  }
  // LN epilogue: each row's 128 cols live in 16 consecutive lanes (same ty)
  float g[8], bta[8];
  #pragma unroll
  for (int j = 0; j < 8; ++j) { g[j] = gamma[tx * 8 + j]; bta[j] = beta[tx * 8 + j]; }
  #pragma unroll
  for (int i = 0; i < 4; ++i) {
    float s = 0.f, sq = 0.f;
    #pragma unroll
    for (int j = 0; j < 8; ++j) { s += acc[i][j]; sq += acc[i][j] * acc[i][j]; }
    #pragma unroll
    for (int m = 1; m < 16; m <<= 1) {
      s += __shfl_xor(s, m, 64);
      sq += __shfl_xor(sq, m, 64);
    }
    float mean = s * (1.0f / 128.0f);
    float var = sq * (1.0f / 128.0f) - mean * mean;
    float rs = 1.0f / sqrtf(var + 1e-5f);
    float o[8];
    #pragma unroll
    for (int j = 0; j < 8; ++j) o[j] = (acc[i][j] - mean) * rs * g[j] + bta[j];
    float* dst = &Q[(size_t)(m0 + ty * 4 + i) * DQ + n0 + tx * 8];
    *(float4*)dst = make_float4(o[0], o[1], o[2], o[3]);
    *(float4*)(dst + 4) = make_float4(o[4], o[5], o[6], o[7]);
  }
}

// ---------------- dots (tiled fp32 GEMM) + stage-1 top-32-of-256, fused ----------------
// Block: 512 threads, one (hp, 32-token chunk). M=32 tok, N=256 keys, K=128.
__global__ __launch_bounds__(512) void dots_sel(
    const float* __restrict__ Q, const float* __restrict__ keys,
    float* __restrict__ s1s, int* __restrict__ s1i) {
  const int hp = blockIdx.x;       // h*2+p
  const int chunk = blockIdx.y;    // 0..63
  const int h = hp >> 1, p = hp & 1;
  const int t0 = chunk * 32;
  __shared__ float Qs[32 * 132];   // [tok][d]
  __shared__ float Bs[16 * 260];   // [k][n] transposed key tile
  __shared__ float Ss[32 * 260];   // [tok][n] scores
  const int tid = threadIdx.x;
  const int w = tid >> 6, lane = tid & 63;
  // stage Q tile: 32 tok x 128 d
  {
    const int tok = tid >> 4, d0 = (tid & 15) * 8;
    const float* src = &Q[(size_t)(t0 + tok) * DQ + p * 1024 + h * 128 + d0];
    *(float4*)&Qs[tok * 132 + d0] = *(const float4*)src;
    *(float4*)&Qs[tok * 132 + d0 + 4] = *(const float4*)(src + 4);
  }
  const int bn = tid >> 1, bkh = (tid & 1) * 8;  // B staging: 256n x 16k
  const float* kbase = keys + ((size_t)(h * NKEYS + bn) * 2 + p) * 128;
  float acc[4][4] = {};  // rows w*4+i, cols lane*4+j
  for (int kt = 0; kt < 128; kt += 16) {
    float4 b0 = *(const float4*)&kbase[kt + bkh];
    float4 b1 = *(const float4*)&kbase[kt + bkh + 4];
    __syncthreads();  // (covers Qs staging on iter 0; prior compute otherwise)
    Bs[(bkh + 0) * 260 + bn] = b0.x; Bs[(bkh + 1) * 260 + bn] = b0.y;
    Bs[(bkh + 2) * 260 + bn] = b0.z; Bs[(bkh + 3) * 260 + bn] = b0.w;
    Bs[(bkh + 4) * 260 + bn] = b1.x; Bs[(bkh + 5) * 260 + bn] = b1.y;
    Bs[(bkh + 6) * 260 + bn] = b1.z; Bs[(bkh + 7) * 260 + bn] = b1.w;
    __syncthreads();
    #pragma unroll
    for (int k4 = 0; k4 < 16; k4 += 4) {
      float4 a0 = *(const float4*)&Qs[(w * 4 + 0) * 132 + kt + k4];  // wave-uniform bcast
      float4 a1 = *(const float4*)&Qs[(w * 4 + 1) * 132 + kt + k4];
      float4 a2 = *(const float4*)&Qs[(w * 4 + 2) * 132 + kt + k4];
      float4 a3 = *(const float4*)&Qs[(w * 4 + 3) * 132 + kt + k4];
      const float a0r[4] = {a0.x, a0.y, a0.z, a0.w};
      const float a1r[4] = {a1.x, a1.y, a1.z, a1.w};
      const float a2r[4] = {a2.x, a2.y, a2.z, a2.w};
      const float a3r[4] = {a3.x, a3.y, a3.z, a3.w};
      #pragma unroll
      for (int kk = 0; kk < 4; ++kk) {
        float4 b4 = *(const float4*)&Bs[(k4 + kk) * 260 + lane * 4];
        const float br[4] = {b4.x, b4.y, b4.z, b4.w};
        #pragma unroll
        for (int j = 0; j < 4; ++j) {
          acc[0][j] += a0r[kk] * br[j];
          acc[1][j] += a1r[kk] * br[j];
          acc[2][j] += a2r[kk] * br[j];
          acc[3][j] += a3r[kk] * br[j];
        }
      }
    }
  }
  #pragma unroll
  for (int i = 0; i < 4; ++i)
    *(float4*)&Ss[(w * 4 + i) * 260 + lane * 4] =
        make_float4(acc[i][0], acc[i][1], acc[i][2], acc[i][3]);
  __syncthreads();
  // selection: wave w handles tokens w*4 .. w*4+3, top-32-of-256 each
  for (int tt = 0; tt < 4; ++tt) {
    const int tok = w * 4 + tt;
    float v[4];
    #pragma unroll
    for (int s = 0; s < 4; ++s) v[s] = Ss[tok * 260 + lane + 64 * s];
    const int inst = (t0 + tok) * 16 + hp;
    for (int r = 0; r < KSEL; ++r) {
      float bv = v[0]; int bi = lane;
      #pragma unroll
      for (int s = 1; s < 4; ++s)
        if (v[s] > bv) { bv = v[s]; bi = lane + 64 * s; }  // > keeps smaller idx on ties
      #pragma unroll
      for (int m = 1; m < 64; m <<= 1) {
        float ov = __shfl_xor(bv, m, 64);
        int oi = __shfl_xor(bi, m, 64);
        if (ov > bv || (ov == bv && oi < bi)) { bv = ov; bi = oi; }
      }
      if ((bi & 63) == lane) v[bi >> 6] = -INFINITY;
      if (lane == r) { s1s[(size_t)inst * KSEL + r] = bv; s1i[(size_t)inst * KSEL + r] = bi; }
    }
  }
}

// ---------------- stage-2: combine 32x32, top-32-of-1024, softmax ----------------
__global__ __launch_bounds__(256) void stage2_kernel(
    const float* __restrict__ s1s, const int* __restrict__ s1i,
    float* __restrict__ wgt, int* __restrict__ vidx) {
  const int th = blockIdx.x * 4 + (threadIdx.x >> 6);
  const int lane = threadIdx.x & 63;
  const int bx = (th * 2) * KSEL;  // p=0
  const int by = bx + KSEL;        // p=1
  const int i = lane >> 1;
  const int j0 = (lane & 1) * 16;
  float sx = s1s[bx + i];
  float cand[16];
  #pragma unroll
  for (int m = 0; m < 16; ++m) cand[m] = sx + s1s[by + j0 + m];
  unsigned valid = 0xffffu;
  float selv = 0.f; int self_ = 0;
  for (int r = 0; r < KSEL; ++r) {
    float bv = -INFINITY; int bm = 0;
    #pragma unroll
    for (int m = 0; m < 16; ++m) {
      bool ok = ((valid >> m) & 1u) != 0;
      if (ok && cand[m] > bv) { bv = cand[m]; bm = m; }
    }
    int bf = i * 32 + j0 + bm;
    #pragma unroll
    for (int m = 1; m < 64; m <<= 1) {
      float ov = __shfl_xor(bv, m, 64);
      int of = __shfl_xor(bf, m, 64);
      if (ov > bv || (ov == bv && of < bf)) { bv = ov; bf = of; }
    }
    int owner = ((bf >> 5) << 1) | ((bf >> 4) & 1);
    if (lane == owner) valid &= ~(1u << (bf & 15));
    if (lane == r) { selv = bv; self_ = bf; }
  }
  float mx = __shfl(selv, 0, 64);
  float e = (lane < KSEL) ? expf(selv - mx) : 0.f;
  float es = e;
  #pragma unroll
  for (int m = 1; m < 64; m <<= 1) es += __shfl_xor(es, m, 64);
  if (lane < KSEL) {
    int ci = self_ >> 5, cj = self_ & 31;
    int vi = s1i[bx + ci] * NKEYS + s1i[by + cj];
    wgt[(size_t)th * KSEL + lane] = e / es;
    vidx[(size_t)th * KSEL + lane] = vi;
  }
}

// ---------------- gather + weighted sum (2 tokens/block, float4 lanes) ----------------
__global__ __launch_bounds__(256) void gather_kernel(
    const float* __restrict__ wgt, const int* __restrict__ vidx,
    const float* __restrict__ values, float* __restrict__ out) {
  const int tp = blockIdx.x;  // token pair
  const int tid = threadIdx.x;
  __shared__ float ws_[512];
  __shared__ int vs_[512];
  ws_[tid] = wgt[(size_t)tp * 512 + tid];
  ws_[tid + 256] = wgt[(size_t)tp * 512 + tid + 256];
  vs_[tid] = vidx[(size_t)tp * 512 + tid];
  vs_[tid + 256] = vidx[(size_t)tp * 512 + tid + 256];
  __syncthreads();
  const int sub = tid >> 7;           // which token of the pair
  const int c4 = (tid & 127) * 4;     // 4 cols of 512
  const float* wp = &ws_[sub * 256];
  const int* vp = &vs_[sub * 256];
  float4 a = make_float4(0.f, 0.f, 0.f, 0.f);
  #pragma unroll 4
  for (int e = 0; e < 256; ++e) {
    float4 vv = *(const float4*)(values + (size_t)vp[e] * CDIM + c4);
    float wv = wp[e];
    a.x += wv * vv.x; a.y += wv * vv.y; a.z += wv * vv.z; a.w += wv * vv.w;
  }
  *(float4*)(out + (size_t)(tp * 2 + sub) * CDIM + c4) = a;
}

extern "C" void kernel_launch(void* const* d_in, const int* in_sizes, int n_in,
                              void* d_out, int out_size, void* d_ws, size_t ws_size,
                              hipStream_t stream) {
  const float* X      = (const float*)d_in[0];  // (2,1024,512)
  const float* W      = (const float*)d_in[1];  // (2048,512)
  const float* keys   = (const float*)d_in[2];  // (8,256,2,128)
  const float* values = (const float*)d_in[3];  // (65536,512)
  const float* gamma  = (const float*)d_in[4];  // (128,)
  const float* beta   = (const float*)d_in[5];  // (128,)
  char* ws = (char*)d_ws;
  float* s1s = (float*)(ws);                  // 4 MB
  int*   s1i = (int*)  (ws + (4u << 20));     // 4 MB
  float* wgt = (float*)(ws + (8u << 20));     // 2 MB
  int*   vix = (int*)  (ws + (10u << 20));    // 2 MB
  float* Q   = (float*)(ws + (12u << 20));    // 16 MB  (peak 28 MB, known-good)

  qgemm_ln<<<dim3(32, 16), 256, 0, stream>>>(X, W, gamma, beta, Q);
  dots_sel<<<dim3(16, 64), 512, 0, stream>>>(Q, keys, s1s, s1i);
  stage2_kernel<<<4096, 256, 0, stream>>>(s1s, s1i, wgt, vix);
  gather_kernel<<<1024, 256, 0, stream>>>(wgt, vix, values, (float*)d_out);
}

// Round 4
// 491.875 us; speedup vs baseline: 1.7846x; 1.6996x over previous
//
#include <hip/hip_runtime.h>
#include <math.h>

#define DQ 2048
#define CDIM 512
#define NKEYS 256
#define KSEL 32

// composite order: rank a before b iff (a.s > b.s) || (a.s == b.s && a.i < b.i)
__device__ __forceinline__ bool rank_before(float as, int ai, float bs, int bi) {
  return (as > bs) || (as == bs && ai < bi);
}

// ---------------- q = LN(X * Wq^T) fused (fp32 vector GEMM + groupwise LN) ----------------
__global__ __launch_bounds__(256) void qgemm_ln(
    const float* __restrict__ X, const float* __restrict__ W,
    const float* __restrict__ gamma, const float* __restrict__ beta,
    float* __restrict__ Q) {
  __shared__ float As[16 * 68];   // [k][m]
  __shared__ float Bs[16 * 132];  // [k][n]
  const int tid = threadIdx.x;
  const int m0 = blockIdx.x * 64, n0 = blockIdx.y * 128;
  const int tx = tid & 15, ty = tid >> 4;
  const int am = tid >> 2, ak = (tid & 3) * 4;
  const int bn = tid >> 1, bk = (tid & 1) * 8;
  float acc[4][8] = {};
  for (int kt = 0; kt < CDIM; kt += 16) {
    float4 av  = *(const float4*)&X[(size_t)(m0 + am) * CDIM + kt + ak];
    float4 bv0 = *(const float4*)&W[(size_t)(n0 + bn) * CDIM + kt + bk];
    float4 bv1 = *(const float4*)&W[(size_t)(n0 + bn) * CDIM + kt + bk + 4];
    __syncthreads();
    As[(ak + 0) * 68 + am] = av.x; As[(ak + 1) * 68 + am] = av.y;
    As[(ak + 2) * 68 + am] = av.z; As[(ak + 3) * 68 + am] = av.w;
    Bs[(bk + 0) * 132 + bn] = bv0.x; Bs[(bk + 1) * 132 + bn] = bv0.y;
    Bs[(bk + 2) * 132 + bn] = bv0.z; Bs[(bk + 3) * 132 + bn] = bv0.w;
    Bs[(bk + 4) * 132 + bn] = bv1.x; Bs[(bk + 5) * 132 + bn] = bv1.y;
    Bs[(bk + 6) * 132 + bn] = bv1.z; Bs[(bk + 7) * 132 + bn] = bv1.w;
    __syncthreads();
    #pragma unroll
    for (int kk = 0; kk < 16; ++kk) {
      float4 a4  = *(const float4*)&As[kk * 68 + ty * 4];
      float4 b4a = *(const float4*)&Bs[kk * 132 + tx * 8];
      float4 b4b = *(const float4*)&Bs[kk * 132 + tx * 8 + 4];
      const float ar[4] = {a4.x, a4.y, a4.z, a4.w};
      const float br[8] = {b4a.x, b4a.y, b4a.z, b4a.w, b4b.x, b4b.y, b4b.z, b4b.w};
      #pragma unroll
      for (int i = 0; i < 4; ++i)
        #pragma unroll
        for (int j = 0; j < 8; ++j)
          acc[i][j] += ar[i] * br[j];
    }
  }
  float g[8], bta[8];
  #pragma unroll
  for (int j = 0; j < 8; ++j) { g[j] = gamma[tx * 8 + j]; bta[j] = beta[tx * 8 + j]; }
  #pragma unroll
  for (int i = 0; i < 4; ++i) {
    float s = 0.f, sq = 0.f;
    #pragma unroll
    for (int j = 0; j < 8; ++j) { s += acc[i][j]; sq += acc[i][j] * acc[i][j]; }
    #pragma unroll
    for (int m = 1; m < 16; m <<= 1) {
      s += __shfl_xor(s, m, 64);
      sq += __shfl_xor(sq, m, 64);
    }
    float mean = s * (1.0f / 128.0f);
    float var = sq * (1.0f / 128.0f) - mean * mean;
    float rs = 1.0f / sqrtf(var + 1e-5f);
    float o[8];
    #pragma unroll
    for (int j = 0; j < 8; ++j) o[j] = (acc[i][j] - mean) * rs * g[j] + bta[j];
    float* dst = &Q[(size_t)(m0 + ty * 4 + i) * DQ + n0 + tx * 8];
    *(float4*)dst = make_float4(o[0], o[1], o[2], o[3]);
    *(float4*)(dst + 4) = make_float4(o[4], o[5], o[6], o[7]);
  }
}

// ---------------- dots (tiled fp32 GEMM) + in-register bitonic top-32 ----------------
// Block: 512 thr, one (hp, 32-token chunk). Wave w owns tokens w*4..w*4+3;
// lane l holds keys {4l..4l+3} of each owned token's 256-score row.
__global__ __launch_bounds__(512, 6) void dots_sel(
    const float* __restrict__ Q, const float* __restrict__ keys,
    float* __restrict__ s1s, int* __restrict__ s1i) {
  const int hp = blockIdx.x;
  const int chunk = blockIdx.y;
  const int h = hp >> 1, p = hp & 1;
  const int t0 = chunk * 32;
  __shared__ float Qs[32 * 132];
  __shared__ float Bs[16 * 260];
  const int tid = threadIdx.x;
  const int w = tid >> 6, lane = tid & 63;
  {
    const int tok = tid >> 4, d0 = (tid & 15) * 8;
    const float* src = &Q[(size_t)(t0 + tok) * DQ + p * 1024 + h * 128 + d0];
    *(float4*)&Qs[tok * 132 + d0] = *(const float4*)src;
    *(float4*)&Qs[tok * 132 + d0 + 4] = *(const float4*)(src + 4);
  }
  const int bn = tid >> 1, bkh = (tid & 1) * 8;
  const float* kbase = keys + ((size_t)(h * NKEYS + bn) * 2 + p) * 128;
  float acc[4][4] = {};
  for (int kt = 0; kt < 128; kt += 16) {
    float4 b0 = *(const float4*)&kbase[kt + bkh];
    float4 b1 = *(const float4*)&kbase[kt + bkh + 4];
    __syncthreads();
    Bs[(bkh + 0) * 260 + bn] = b0.x; Bs[(bkh + 1) * 260 + bn] = b0.y;
    Bs[(bkh + 2) * 260 + bn] = b0.z; Bs[(bkh + 3) * 260 + bn] = b0.w;
    Bs[(bkh + 4) * 260 + bn] = b1.x; Bs[(bkh + 5) * 260 + bn] = b1.y;
    Bs[(bkh + 6) * 260 + bn] = b1.z; Bs[(bkh + 7) * 260 + bn] = b1.w;
    __syncthreads();
    #pragma unroll
    for (int k4 = 0; k4 < 16; k4 += 4) {
      float4 a0 = *(const float4*)&Qs[(w * 4 + 0) * 132 + kt + k4];
      float4 a1 = *(const float4*)&Qs[(w * 4 + 1) * 132 + kt + k4];
      float4 a2 = *(const float4*)&Qs[(w * 4 + 2) * 132 + kt + k4];
      float4 a3 = *(const float4*)&Qs[(w * 4 + 3) * 132 + kt + k4];
      const float a0r[4] = {a0.x, a0.y, a0.z, a0.w};
      const float a1r[4] = {a1.x, a1.y, a1.z, a1.w};
      const float a2r[4] = {a2.x, a2.y, a2.z, a2.w};
      const float a3r[4] = {a3.x, a3.y, a3.z, a3.w};
      #pragma unroll
      for (int kk = 0; kk < 4; ++kk) {
        float4 b4 = *(const float4*)&Bs[(k4 + kk) * 260 + lane * 4];
        const float br[4] = {b4.x, b4.y, b4.z, b4.w};
        #pragma unroll
        for (int j = 0; j < 4; ++j) {
          acc[0][j] += a0r[kk] * br[j];
          acc[1][j] += a1r[kk] * br[j];
          acc[2][j] += a2r[kk] * br[j];
          acc[3][j] += a3r[kk] * br[j];
        }
      }
    }
  }
  // ---- per-token bitonic sort of 256 (score,idx) pairs, 4/lane blocked ----
  for (int i = 0; i < 4; ++i) {
    float s[4]; int id[4];
    #pragma unroll
    for (int r = 0; r < 4; ++r) { s[r] = acc[i][r]; id[r] = lane * 4 + r; }
    // intra-lane compare-exchange helper (a,b), dirDown=dd
    #define CE(a, b, dd)                                                       \
      {                                                                        \
        bool sw = (dd) ? rank_before(s[a], id[a], s[b], id[b])                 \
                       : rank_before(s[b], id[b], s[a], id[a]);                \
        if (sw) {                                                              \
          float ts = s[a]; s[a] = s[b]; s[b] = ts;                             \
          int ti = id[a]; id[a] = id[b]; id[b] = ti;                           \
        }                                                                      \
      }
    // cross-lane pass, partner = lane^L, dirDown=dd
    #define CROSS(L, dd)                                                       \
      {                                                                        \
        bool amHigh = (lane & (L)) != 0;                                       \
        bool flip = amHigh != (dd);                                            \
        _Pragma("unroll")                                                      \
        for (int r = 0; r < 4; ++r) {                                          \
          float os = __shfl_xor(s[r], (L), 64);                                \
          int oi = __shfl_xor(id[r], (L), 64);                                 \
          bool take = rank_before(os, oi, s[r], id[r]) != flip;                \
          if (take) { s[r] = os; id[r] = oi; }                                 \
        }                                                                      \
      }
    // k=2
    CE(0, 1, false); CE(2, 3, true);
    // k=4
    {
      bool dd = (lane & 1) != 0;
      CE(0, 2, dd); CE(1, 3, dd); CE(0, 1, dd); CE(2, 3, dd);
    }
    // k=8..256
    #pragma unroll
    for (int K = 8; K <= 256; K <<= 1) {
      bool dd = (lane & (K >> 2)) != 0;
      #pragma unroll
      for (int L = K >> 3; L >= 1; L >>= 1) CROSS(L, dd);
      CE(0, 2, dd); CE(1, 3, dd); CE(0, 1, dd); CE(2, 3, dd);
    }
    #undef CE
    #undef CROSS
    const int inst = (t0 + w * 4 + i) * 16 + hp;
    if (lane < 8) {
      *(float4*)&s1s[(size_t)inst * KSEL + lane * 4] = make_float4(s[0], s[1], s[2], s[3]);
      *(int4*)&s1i[(size_t)inst * KSEL + lane * 4] = make_int4(id[0], id[1], id[2], id[3]);
    }
  }
}

// ---------------- stage-2: pruned 119-candidate bitonic top-32 + softmax ----------------
// candidates (i,j) with (i+1)*(j+1) <= 32 — all others have >=33 dominators
// (score >= theirs, smaller flat index) so can never be in the top-32, even w/ ties.
__constant__ unsigned short slot_ij[128] = {
  0,1,2,3,4,5,6,7,8,9,10,11,12,13,14,15,16,17,18,19,20,21,22,23,24,25,26,27,28,29,30,31,
  32,33,34,35,36,37,38,39,40,41,42,43,44,45,46,47,
  64,65,66,67,68,69,70,71,72,73,
  96,97,98,99,100,101,102,103,
  128,129,130,131,132,133,
  160,161,162,163,164,
  192,193,194,195,
  224,225,226,227,
  256,257,258,
  288,289,290,
  320,321, 352,353, 384,385, 416,417, 448,449, 480,481,
  512,544,576,608,640,672,704,736,768,800,832,864,896,928,960,992,
  0xFFFF,0xFFFF,0xFFFF,0xFFFF,0xFFFF,0xFFFF,0xFFFF,0xFFFF,0xFFFF
};

__global__ __launch_bounds__(256) void stage2_kernel(
    const float* __restrict__ s1s, const int* __restrict__ s1i,
    float* __restrict__ wgt, int* __restrict__ vidx) {
  const int th = blockIdx.x * 4 + (threadIdx.x >> 6);
  const int lane = threadIdx.x & 63;
  const int bx = th * 64;  // p=0 base in s1s/s1i
  const int by = bx + 32;  // p=1
  float s[2]; int id[2];
  #pragma unroll
  for (int r = 0; r < 2; ++r) {
    int sl = slot_ij[lane * 2 + r];
    if (sl != 0xFFFF) {
      s[r] = s1s[bx + (sl >> 5)] + s1s[by + (sl & 31)];
      id[r] = sl;
    } else {
      s[r] = -INFINITY; id[r] = 0x7fffffff;
    }
  }
  // bitonic sort of 128, 2/lane blocked: element e = lane*2 + r
  #define CE2(dd)                                                              \
    {                                                                          \
      bool sw = (dd) ? rank_before(s[0], id[0], s[1], id[1])                   \
                     : rank_before(s[1], id[1], s[0], id[0]);                  \
      if (sw) {                                                                \
        float ts = s[0]; s[0] = s[1]; s[1] = ts;                               \
        int ti = id[0]; id[0] = id[1]; id[1] = ti;                             \
      }                                                                        \
    }
  #define CROSS2(L, dd)                                                        \
    {                                                                          \
      bool amHigh = (lane & (L)) != 0;                                         \
      bool flip = amHigh != (dd);                                              \
      _Pragma("unroll")                                                        \
      for (int r = 0; r < 2; ++r) {                                            \
        float os = __shfl_xor(s[r], (L), 64);                                  \
        int oi = __shfl_xor(id[r], (L), 64);                                   \
        bool take = rank_before(os, oi, s[r], id[r]) != flip;                  \
        if (take) { s[r] = os; id[r] = oi; }                                   \
      }                                                                        \
    }
  { bool dd = (lane & 1) != 0; CE2(dd); }  // k=2: e&2 = lane&1
  #pragma unroll
  for (int K = 4; K <= 128; K <<= 1) {
    bool dd = (lane & (K >> 1)) != 0;  // e&K bit = lane bit log2(K)-1
    #pragma unroll
    for (int L = K >> 2; L >= 1; L >>= 1) CROSS2(L, dd);
    CE2(dd);
  }
  #undef CE2
  #undef CROSS2
  // top-32 now in lanes 0..15 (ranks lane*2+r)
  float smax = __shfl(s[0], 0, 64);
  float e0 = 0.f, e1 = 0.f;
  if (lane < 16) { e0 = expf(s[0] - smax); e1 = expf(s[1] - smax); }
  float part = e0 + e1;
  #pragma unroll
  for (int m = 1; m < 16; m <<= 1) part += __shfl_xor(part, m, 64);
  if (lane < 16) {
    int f0 = id[0], f1 = id[1];
    int vi0 = s1i[bx + (f0 >> 5)] * NKEYS + s1i[by + (f0 & 31)];
    int vi1 = s1i[bx + (f1 >> 5)] * NKEYS + s1i[by + (f1 & 31)];
    wgt[(size_t)th * KSEL + lane * 2] = e0 / part;
    wgt[(size_t)th * KSEL + lane * 2 + 1] = e1 / part;
    vidx[(size_t)th * KSEL + lane * 2] = vi0;
    vidx[(size_t)th * KSEL + lane * 2 + 1] = vi1;
  }
}

// ---------------- gather + weighted sum (2 tokens/block, float4 lanes) ----------------
__global__ __launch_bounds__(256) void gather_kernel(
    const float* __restrict__ wgt, const int* __restrict__ vidx,
    const float* __restrict__ values, float* __restrict__ out) {
  const int tp = blockIdx.x;
  const int tid = threadIdx.x;
  __shared__ float ws_[512];
  __shared__ int vs_[512];
  ws_[tid] = wgt[(size_t)tp * 512 + tid];
  ws_[tid + 256] = wgt[(size_t)tp * 512 + tid + 256];
  vs_[tid] = vidx[(size_t)tp * 512 + tid];
  vs_[tid + 256] = vidx[(size_t)tp * 512 + tid + 256];
  __syncthreads();
  const int sub = tid >> 7;
  const int c4 = (tid & 127) * 4;
  const float* wp = &ws_[sub * 256];
  const int* vp = &vs_[sub * 256];
  float4 a = make_float4(0.f, 0.f, 0.f, 0.f);
  #pragma unroll 4
  for (int e = 0; e < 256; ++e) {
    float4 vv = *(const float4*)(values + (size_t)vp[e] * CDIM + c4);
    float wv = wp[e];
    a.x += wv * vv.x; a.y += wv * vv.y; a.z += wv * vv.z; a.w += wv * vv.w;
  }
  *(float4*)(out + (size_t)(tp * 2 + sub) * CDIM + c4) = a;
}

extern "C" void kernel_launch(void* const* d_in, const int* in_sizes, int n_in,
                              void* d_out, int out_size, void* d_ws, size_t ws_size,
                              hipStream_t stream) {
  const float* X      = (const float*)d_in[0];
  const float* W      = (const float*)d_in[1];
  const float* keys   = (const float*)d_in[2];
  const float* values = (const float*)d_in[3];
  const float* gamma  = (const float*)d_in[4];
  const float* beta   = (const float*)d_in[5];
  char* ws = (char*)d_ws;
  float* s1s = (float*)(ws);
  int*   s1i = (int*)  (ws + (4u << 20));
  float* wgt = (float*)(ws + (8u << 20));
  int*   vix = (int*)  (ws + (10u << 20));
  float* Q   = (float*)(ws + (12u << 20));

  qgemm_ln<<<dim3(32, 16), 256, 0, stream>>>(X, W, gamma, beta, Q);
  dots_sel<<<dim3(16, 64), 512, 0, stream>>>(Q, keys, s1s, s1i);
  stage2_kernel<<<4096, 256, 0, stream>>>(s1s, s1i, wgt, vix);
  gather_kernel<<<1024, 256, 0, stream>>>(wgt, vix, values, (float*)d_out);
}

// Round 5
// 445.604 us; speedup vs baseline: 1.9699x; 1.1038x over previous
//
#include <hip/hip_runtime.h>
#include <math.h>

#define DQ 2048
#define CDIM 512
#define NKEYS 256
#define KSEL 32

__device__ __forceinline__ bool rank_before(float as, int ai, float bs, int bi) {
  return (as > bs) || (as == bs && ai < bi);
}
static __device__ __forceinline__ float bf2f(unsigned int u) {
  union { unsigned int i; float f; } v; v.i = u << 16; return v.f;
}
static __device__ __forceinline__ unsigned int f2bf(float f) {
  union { float f; unsigned int i; } v; v.f = f;
  unsigned int r = v.i + 0x7fffu + ((v.i >> 16) & 1u);
  return r >> 16;
}

// ---------------- q = LN(X * Wq^T) fused (fp32 vector GEMM + groupwise LN) ----------------
__global__ __launch_bounds__(256) void qgemm_ln(
    const float* __restrict__ X, const float* __restrict__ W,
    const float* __restrict__ gamma, const float* __restrict__ beta,
    float* __restrict__ Q) {
  __shared__ float As[16 * 68];   // [k][m]
  __shared__ float Bs[16 * 132];  // [k][n]
  const int tid = threadIdx.x;
  const int m0 = blockIdx.x * 64, n0 = blockIdx.y * 128;
  const int tx = tid & 15, ty = tid >> 4;
  const int am = tid >> 2, ak = (tid & 3) * 4;
  const int bn = tid >> 1, bk = (tid & 1) * 8;
  float acc[4][8] = {};
  // software prefetch of first tile
  float4 av  = *(const float4*)&X[(size_t)(m0 + am) * CDIM + ak];
  float4 bv0 = *(const float4*)&W[(size_t)(n0 + bn) * CDIM + bk];
  float4 bv1 = *(const float4*)&W[(size_t)(n0 + bn) * CDIM + bk + 4];
  for (int kt = 0; kt < CDIM; kt += 16) {
    __syncthreads();
    As[(ak + 0) * 68 + am] = av.x; As[(ak + 1) * 68 + am] = av.y;
    As[(ak + 2) * 68 + am] = av.z; As[(ak + 3) * 68 + am] = av.w;
    Bs[(bk + 0) * 132 + bn] = bv0.x; Bs[(bk + 1) * 132 + bn] = bv0.y;
    Bs[(bk + 2) * 132 + bn] = bv0.z; Bs[(bk + 3) * 132 + bn] = bv0.w;
    Bs[(bk + 4) * 132 + bn] = bv1.x; Bs[(bk + 5) * 132 + bn] = bv1.y;
    Bs[(bk + 6) * 132 + bn] = bv1.z; Bs[(bk + 7) * 132 + bn] = bv1.w;
    __syncthreads();
    if (kt + 16 < CDIM) {  // prefetch next tile; latency hides behind compute
      av  = *(const float4*)&X[(size_t)(m0 + am) * CDIM + kt + 16 + ak];
      bv0 = *(const float4*)&W[(size_t)(n0 + bn) * CDIM + kt + 16 + bk];
      bv1 = *(const float4*)&W[(size_t)(n0 + bn) * CDIM + kt + 16 + bk + 4];
    }
    #pragma unroll
    for (int kk = 0; kk < 16; ++kk) {
      float4 a4  = *(const float4*)&As[kk * 68 + ty * 4];
      float4 b4a = *(const float4*)&Bs[kk * 132 + tx * 8];
      float4 b4b = *(const float4*)&Bs[kk * 132 + tx * 8 + 4];
      const float ar[4] = {a4.x, a4.y, a4.z, a4.w};
      const float br[8] = {b4a.x, b4a.y, b4a.z, b4a.w, b4b.x, b4b.y, b4b.z, b4b.w};
      #pragma unroll
      for (int i = 0; i < 4; ++i)
        #pragma unroll
        for (int j = 0; j < 8; ++j)
          acc[i][j] += ar[i] * br[j];
    }
  }
  float g[8], bta[8];
  #pragma unroll
  for (int j = 0; j < 8; ++j) { g[j] = gamma[tx * 8 + j]; bta[j] = beta[tx * 8 + j]; }
  #pragma unroll
  for (int i = 0; i < 4; ++i) {
    float s = 0.f, sq = 0.f;
    #pragma unroll
    for (int j = 0; j < 8; ++j) { s += acc[i][j]; sq += acc[i][j] * acc[i][j]; }
    #pragma unroll
    for (int m = 1; m < 16; m <<= 1) {
      s += __shfl_xor(s, m, 64);
      sq += __shfl_xor(sq, m, 64);
    }
    float mean = s * (1.0f / 128.0f);
    float var = sq * (1.0f / 128.0f) - mean * mean;
    float rs = 1.0f / sqrtf(var + 1e-5f);
    float o[8];
    #pragma unroll
    for (int j = 0; j < 8; ++j) o[j] = (acc[i][j] - mean) * rs * g[j] + bta[j];
    float* dst = &Q[(size_t)(m0 + ty * 4 + i) * DQ + n0 + tx * 8];
    *(float4*)dst = make_float4(o[0], o[1], o[2], o[3]);
    *(float4*)(dst + 4) = make_float4(o[4], o[5], o[6], o[7]);
  }
}

// ---------------- dots (tiled fp32 GEMM) + in-register bitonic top-32 ----------------
__global__ __launch_bounds__(512, 6) void dots_sel(
    const float* __restrict__ Q, const float* __restrict__ keys,
    float* __restrict__ s1s, int* __restrict__ s1i) {
  const int hp = blockIdx.x;
  const int chunk = blockIdx.y;
  const int h = hp >> 1, p = hp & 1;
  const int t0 = chunk * 32;
  __shared__ float Qs[32 * 132];
  __shared__ float Bs[16 * 260];
  const int tid = threadIdx.x;
  const int w = tid >> 6, lane = tid & 63;
  {
    const int tok = tid >> 4, d0 = (tid & 15) * 8;
    const float* src = &Q[(size_t)(t0 + tok) * DQ + p * 1024 + h * 128 + d0];
    *(float4*)&Qs[tok * 132 + d0] = *(const float4*)src;
    *(float4*)&Qs[tok * 132 + d0 + 4] = *(const float4*)(src + 4);
  }
  const int bn = tid >> 1, bkh = (tid & 1) * 8;
  const float* kbase = keys + ((size_t)(h * NKEYS + bn) * 2 + p) * 128;
  float acc[4][4] = {};
  float4 b0 = *(const float4*)&kbase[bkh];
  float4 b1 = *(const float4*)&kbase[bkh + 4];
  for (int kt = 0; kt < 128; kt += 16) {
    __syncthreads();
    Bs[(bkh + 0) * 260 + bn] = b0.x; Bs[(bkh + 1) * 260 + bn] = b0.y;
    Bs[(bkh + 2) * 260 + bn] = b0.z; Bs[(bkh + 3) * 260 + bn] = b0.w;
    Bs[(bkh + 4) * 260 + bn] = b1.x; Bs[(bkh + 5) * 260 + bn] = b1.y;
    Bs[(bkh + 6) * 260 + bn] = b1.z; Bs[(bkh + 7) * 260 + bn] = b1.w;
    __syncthreads();
    if (kt + 16 < 128) {  // prefetch next key K-slab
      b0 = *(const float4*)&kbase[kt + 16 + bkh];
      b1 = *(const float4*)&kbase[kt + 16 + bkh + 4];
    }
    #pragma unroll
    for (int k4 = 0; k4 < 16; k4 += 4) {
      float4 a0 = *(const float4*)&Qs[(w * 4 + 0) * 132 + kt + k4];
      float4 a1 = *(const float4*)&Qs[(w * 4 + 1) * 132 + kt + k4];
      float4 a2 = *(const float4*)&Qs[(w * 4 + 2) * 132 + kt + k4];
      float4 a3 = *(const float4*)&Qs[(w * 4 + 3) * 132 + kt + k4];
      const float a0r[4] = {a0.x, a0.y, a0.z, a0.w};
      const float a1r[4] = {a1.x, a1.y, a1.z, a1.w};
      const float a2r[4] = {a2.x, a2.y, a2.z, a2.w};
      const float a3r[4] = {a3.x, a3.y, a3.z, a3.w};
      #pragma unroll
      for (int kk = 0; kk < 4; ++kk) {
        float4 b4 = *(const float4*)&Bs[(k4 + kk) * 260 + lane * 4];
        const float br[4] = {b4.x, b4.y, b4.z, b4.w};
        #pragma unroll
        for (int j = 0; j < 4; ++j) {
          acc[0][j] += a0r[kk] * br[j];
          acc[1][j] += a1r[kk] * br[j];
          acc[2][j] += a2r[kk] * br[j];
          acc[3][j] += a3r[kk] * br[j];
        }
      }
    }
  }
  for (int i = 0; i < 4; ++i) {
    float s[4]; int id[4];
    #pragma unroll
    for (int r = 0; r < 4; ++r) { s[r] = acc[i][r]; id[r] = lane * 4 + r; }
    #define CE(a, b, dd)                                                       \
      {                                                                        \
        bool sw = (dd) ? rank_before(s[a], id[a], s[b], id[b])                 \
                       : rank_before(s[b], id[b], s[a], id[a]);                \
        if (sw) {                                                              \
          float ts = s[a]; s[a] = s[b]; s[b] = ts;                             \
          int ti = id[a]; id[a] = id[b]; id[b] = ti;                           \
        }                                                                      \
      }
    #define CROSS(L, dd)                                                       \
      {                                                                        \
        bool amHigh = (lane & (L)) != 0;                                       \
        bool flip = amHigh != (dd);                                            \
        _Pragma("unroll")                                                      \
        for (int r = 0; r < 4; ++r) {                                          \
          float os = __shfl_xor(s[r], (L), 64);                                \
          int oi = __shfl_xor(id[r], (L), 64);                                 \
          bool take = rank_before(os, oi, s[r], id[r]) != flip;                \
          if (take) { s[r] = os; id[r] = oi; }                                 \
        }                                                                      \
      }
    CE(0, 1, false); CE(2, 3, true);
    {
      bool dd = (lane & 1) != 0;
      CE(0, 2, dd); CE(1, 3, dd); CE(0, 1, dd); CE(2, 3, dd);
    }
    #pragma unroll
    for (int K = 8; K <= 256; K <<= 1) {
      bool dd = (lane & (K >> 2)) != 0;
      #pragma unroll
      for (int L = K >> 3; L >= 1; L >>= 1) CROSS(L, dd);
      CE(0, 2, dd); CE(1, 3, dd); CE(0, 1, dd); CE(2, 3, dd);
    }
    #undef CE
    #undef CROSS
    const int inst = (t0 + w * 4 + i) * 16 + hp;
    if (lane < 8) {
      *(float4*)&s1s[(size_t)inst * KSEL + lane * 4] = make_float4(s[0], s[1], s[2], s[3]);
      *(int4*)&s1i[(size_t)inst * KSEL + lane * 4] = make_int4(id[0], id[1], id[2], id[3]);
    }
  }
}

// ---------------- stage-2: pruned 119-candidate bitonic top-32 + softmax ----------------
__constant__ unsigned short slot_ij[128] = {
  0,1,2,3,4,5,6,7,8,9,10,11,12,13,14,15,16,17,18,19,20,21,22,23,24,25,26,27,28,29,30,31,
  32,33,34,35,36,37,38,39,40,41,42,43,44,45,46,47,
  64,65,66,67,68,69,70,71,72,73,
  96,97,98,99,100,101,102,103,
  128,129,130,131,132,133,
  160,161,162,163,164,
  192,193,194,195,
  224,225,226,227,
  256,257,258,
  288,289,290,
  320,321, 352,353, 384,385, 416,417, 448,449, 480,481,
  512,544,576,608,640,672,704,736,768,800,832,864,896,928,960,992,
  0xFFFF,0xFFFF,0xFFFF,0xFFFF,0xFFFF,0xFFFF,0xFFFF,0xFFFF,0xFFFF
};

__global__ __launch_bounds__(256) void stage2_kernel(
    const float* __restrict__ s1s, const int* __restrict__ s1i,
    float* __restrict__ wgt, int* __restrict__ vidx) {
  const int th = blockIdx.x * 4 + (threadIdx.x >> 6);
  const int lane = threadIdx.x & 63;
  const int bx = th * 64;
  const int by = bx + 32;
  float s[2]; int id[2];
  #pragma unroll
  for (int r = 0; r < 2; ++r) {
    int sl = slot_ij[lane * 2 + r];
    if (sl != 0xFFFF) {
      s[r] = s1s[bx + (sl >> 5)] + s1s[by + (sl & 31)];
      id[r] = sl;
    } else {
      s[r] = -INFINITY; id[r] = 0x7fffffff;
    }
  }
  #define CE2(dd)                                                              \
    {                                                                          \
      bool sw = (dd) ? rank_before(s[0], id[0], s[1], id[1])                   \
                     : rank_before(s[1], id[1], s[0], id[0]);                  \
      if (sw) {                                                                \
        float ts = s[0]; s[0] = s[1]; s[1] = ts;                               \
        int ti = id[0]; id[0] = id[1]; id[1] = ti;                             \
      }                                                                        \
    }
  #define CROSS2(L, dd)                                                        \
    {                                                                          \
      bool amHigh = (lane & (L)) != 0;                                         \
      bool flip = amHigh != (dd);                                              \
      _Pragma("unroll")                                                        \
      for (int r = 0; r < 2; ++r) {                                            \
        float os = __shfl_xor(s[r], (L), 64);                                  \
        int oi = __shfl_xor(id[r], (L), 64);                                   \
        bool take = rank_before(os, oi, s[r], id[r]) != flip;                  \
        if (take) { s[r] = os; id[r] = oi; }                                   \
      }                                                                        \
    }
  { bool dd = (lane & 1) != 0; CE2(dd); }
  #pragma unroll
  for (int K = 4; K <= 128; K <<= 1) {
    bool dd = (lane & (K >> 1)) != 0;
    #pragma unroll
    for (int L = K >> 2; L >= 1; L >>= 1) CROSS2(L, dd);
    CE2(dd);
  }
  #undef CE2
  #undef CROSS2
  float smax = __shfl(s[0], 0, 64);
  float e0 = 0.f, e1 = 0.f;
  if (lane < 16) { e0 = expf(s[0] - smax); e1 = expf(s[1] - smax); }
  float part = e0 + e1;
  #pragma unroll
  for (int m = 1; m < 16; m <<= 1) part += __shfl_xor(part, m, 64);
  if (lane < 16) {
    int f0 = id[0], f1 = id[1];
    int vi0 = s1i[bx + (f0 >> 5)] * NKEYS + s1i[by + (f0 & 31)];
    int vi1 = s1i[bx + (f1 >> 5)] * NKEYS + s1i[by + (f1 & 31)];
    wgt[(size_t)th * KSEL + lane * 2] = e0 / part;
    wgt[(size_t)th * KSEL + lane * 2 + 1] = e1 / part;
    vidx[(size_t)th * KSEL + lane * 2] = vi0;
    vidx[(size_t)th * KSEL + lane * 2 + 1] = vi1;
  }
}

// ---------------- values fp32 -> bf16 (RNE) one-pass convert ----------------
__global__ __launch_bounds__(256) void convert_values(
    const float* __restrict__ values, unsigned int* __restrict__ vbf) {
  const size_t g = ((size_t)blockIdx.x * 256 + threadIdx.x) * 8;
  float4 a = *(const float4*)(values + g);
  float4 b = *(const float4*)(values + g + 4);
  uint4 pk;
  pk.x = f2bf(a.x) | (f2bf(a.y) << 16);
  pk.y = f2bf(a.z) | (f2bf(a.w) << 16);
  pk.z = f2bf(b.x) | (f2bf(b.y) << 16);
  pk.w = f2bf(b.z) | (f2bf(b.w) << 16);
  *(uint4*)(vbf + g / 2) = pk;
}

// ---------------- gather bf16: wave-per-row, 4 L3 phases ----------------
__global__ __launch_bounds__(256) void gather_bf16(
    const float* __restrict__ wgt, const int* __restrict__ vidx,
    const unsigned short* __restrict__ vbf, float* __restrict__ out) {
  const int t = blockIdx.x;
  const int tid = threadIdx.x, w = tid >> 6, lane = tid & 63;
  __shared__ float ws_[256];
  __shared__ int vs_[256];
  __shared__ float part[4 * 520];
  ws_[tid] = wgt[(size_t)t * 256 + tid];
  vs_[tid] = vidx[(size_t)t * 256 + tid];
  __syncthreads();
  float acc[8] = {};
  const int c0 = lane * 8;
  #pragma unroll 1
  for (int phase = 0; phase < 4; ++phase) {
    for (int e = w; e < 256; e += 4) {
      const int row = vs_[e];                 // wave-uniform scalar
      if ((row >> 14) != phase) continue;     // uniform branch, no divergence
      const float wv = ws_[e];
      uint4 pk = *(const uint4*)(vbf + (size_t)row * CDIM + c0);
      acc[0] += wv * bf2f(pk.x & 0xffff); acc[1] += wv * bf2f(pk.x >> 16);
      acc[2] += wv * bf2f(pk.y & 0xffff); acc[3] += wv * bf2f(pk.y >> 16);
      acc[4] += wv * bf2f(pk.z & 0xffff); acc[5] += wv * bf2f(pk.z >> 16);
      acc[6] += wv * bf2f(pk.w & 0xffff); acc[7] += wv * bf2f(pk.w >> 16);
    }
  }
  #pragma unroll
  for (int j = 0; j < 8; j += 4)
    *(float4*)&part[w * 520 + c0 + j] =
        make_float4(acc[j], acc[j + 1], acc[j + 2], acc[j + 3]);
  __syncthreads();
  const int c2 = tid * 2;
  float r0 = part[c2] + part[520 + c2] + part[1040 + c2] + part[1560 + c2];
  float r1 = part[c2 + 1] + part[520 + c2 + 1] + part[1040 + c2 + 1] + part[1560 + c2 + 1];
  *(float2*)(out + (size_t)t * CDIM + c2) = make_float2(r0, r1);
}

// ---------------- fallback fp32 gather (round-4, for small ws) ----------------
__global__ __launch_bounds__(256) void gather_kernel(
    const float* __restrict__ wgt, const int* __restrict__ vidx,
    const float* __restrict__ values, float* __restrict__ out) {
  const int tp = blockIdx.x;
  const int tid = threadIdx.x;
  __shared__ float ws_[512];
  __shared__ int vs_[512];
  ws_[tid] = wgt[(size_t)tp * 512 + tid];
  ws_[tid + 256] = wgt[(size_t)tp * 512 + tid + 256];
  vs_[tid] = vidx[(size_t)tp * 512 + tid];
  vs_[tid + 256] = vidx[(size_t)tp * 512 + tid + 256];
  __syncthreads();
  const int sub = tid >> 7;
  const int c4 = (tid & 127) * 4;
  const float* wp = &ws_[sub * 256];
  const int* vp = &vs_[sub * 256];
  float4 a = make_float4(0.f, 0.f, 0.f, 0.f);
  #pragma unroll 4
  for (int e = 0; e < 256; ++e) {
    float4 vv = *(const float4*)(values + (size_t)vp[e] * CDIM + c4);
    float wv = wp[e];
    a.x += wv * vv.x; a.y += wv * vv.y; a.z += wv * vv.z; a.w += wv * vv.w;
  }
  *(float4*)(out + (size_t)(tp * 2 + sub) * CDIM + c4) = a;
}

extern "C" void kernel_launch(void* const* d_in, const int* in_sizes, int n_in,
                              void* d_out, int out_size, void* d_ws, size_t ws_size,
                              hipStream_t stream) {
  const float* X      = (const float*)d_in[0];
  const float* W      = (const float*)d_in[1];
  const float* keys   = (const float*)d_in[2];
  const float* values = (const float*)d_in[3];
  const float* gamma  = (const float*)d_in[4];
  const float* beta   = (const float*)d_in[5];
  char* ws = (char*)d_ws;
  float* s1s = (float*)(ws);                  // 0..4 MB
  int*   s1i = (int*)  (ws + (4u << 20));     // 4..8 MB
  float* wgt = (float*)(ws + (8u << 20));     // 8..10 MB
  int*   vix = (int*)  (ws + (10u << 20));    // 10..12 MB
  float* Q   = (float*)(ws + (12u << 20));    // 12..28 MB (dead after dots_sel)
  unsigned int* vbf = (unsigned int*)(ws + (12u << 20));  // 12..76 MB (overlaps dead Q)

  const bool bf16_path = ws_size >= (76u << 20);

  qgemm_ln<<<dim3(32, 16), 256, 0, stream>>>(X, W, gamma, beta, Q);
  dots_sel<<<dim3(16, 64), 512, 0, stream>>>(Q, keys, s1s, s1i);
  stage2_kernel<<<4096, 256, 0, stream>>>(s1s, s1i, wgt, vix);
  if (bf16_path) {
    convert_values<<<16384, 256, 0, stream>>>(values, vbf);  // after dots_sel: Q is dead
    gather_bf16<<<2048, 256, 0, stream>>>(wgt, vix, (const unsigned short*)vbf, (float*)d_out);
  } else {
    gather_kernel<<<1024, 256, 0, stream>>>(wgt, vix, values, (float*)d_out);
  }
}